// Round 11
// baseline (6115.266 us; speedup 1.0000x reference)
//
#include <hip/hip_runtime.h>
#include <stdint.h>

#define B_DIM 256
#define T_DIM 400
#define I_DIMM 256
#define H_DIM 512
#define KH 512      // hidden K
#define KX 256      // input K
#define KU 768      // unified K
#define MT 32       // batch rows per workgroup
#define ACOLS 32    // phase-A (zr) output cols per wg
#define BCOLS 16    // phase-B (n) output cols per wg
#define LDK 776     // padded LDS row pitch (bf16 elems)

#define LDS_USHORTS (2*ACOLS*LDK + 2*BCOLS*LDK)
#define LDS_BYTES   (LDS_USHORTS*2 + 512*4)

// ws layout (bytes)
#define OFF_FLAGA 0
#define OFF_FLAGB 2048
#define OFF_HFRAG 4096
#define FRAG_BYTES (16*16*64*32)          // 512KB
#define OFF_RHFRAG (OFF_HFRAG + FRAG_BYTES)
#define OFF_ZBUF   (OFF_RHFRAG + FRAG_BYTES)
#define OFF_XFRAG  (OFF_ZBUF + B_DIM*H_DIM*4)
#define XFRAG_BYTES ((size_t)T_DIM*16*8*2048)          // 100 MB
#define WS_NEED    ((size_t)OFF_XFRAG + XFRAG_BYTES)

typedef unsigned long long u64;
typedef __attribute__((ext_vector_type(8))) short short8v;
typedef __attribute__((ext_vector_type(4))) float f32x4;
typedef __attribute__((ext_vector_type(2))) u64 u64x2;

__device__ __forceinline__ unsigned short f2bf(float f){
  unsigned u = __builtin_bit_cast(unsigned, f);
  return (unsigned short)((u + 0x7fffu + ((u >> 16) & 1u)) >> 16);   // RNE
}
__device__ __forceinline__ float bf2f(unsigned short u){
  return __builtin_bit_cast(float, ((unsigned)u) << 16);
}
__device__ __forceinline__ f32x4 mfma16(short8v a, short8v b, f32x4 c){
  return __builtin_amdgcn_mfma_f32_16x16x32_bf16(a, b, c, 0, 0, 0);
}

// ---- device-coherent (LLC) access, COMPILER-VISIBLE (spill-safe, auto waitcnt) ----
__device__ __forceinline__ u64 ld64_cg(const void* p){
  return __hip_atomic_load((const u64*)p, __ATOMIC_RELAXED, __HIP_MEMORY_SCOPE_AGENT);
}
__device__ __forceinline__ unsigned ld16_cg(const void* p){
  return (unsigned)__hip_atomic_load((const unsigned short*)p, __ATOMIC_RELAXED,
                                     __HIP_MEMORY_SCOPE_AGENT);
}
__device__ __forceinline__ float ldf_cg(const float* p){
  return __hip_atomic_load(p, __ATOMIC_RELAXED, __HIP_MEMORY_SCOPE_AGENT);
}
__device__ __forceinline__ void st16_cg(void* p, unsigned v){
  asm volatile("global_store_short %0, %1, off sc0 sc1" :: "v"(p), "v"(v) : "memory");
}
__device__ __forceinline__ void stf_cg(float* p, float v){
  asm volatile("global_store_dword %0, %1, off sc0 sc1" :: "v"(p), "v"(v) : "memory");
}
#define VMCNT0() asm volatile("s_waitcnt vmcnt(0)" ::: "memory")

// full-32 spin: lane polls flag (lane&31); monotonic flags -> early positive is valid
__device__ __forceinline__ void spin_ge(const unsigned* f, unsigned target){
  const unsigned* p = f + (threadIdx.x & 31);
  for (;;){
    unsigned v = __hip_atomic_load(p, __ATOMIC_RELAXED, __HIP_MEMORY_SCOPE_AGENT);
    if (__all((int)(v >= target))) break;
    __builtin_amdgcn_s_sleep(1);
  }
  asm volatile("" ::: "memory");
}

// fragment address of element (row, col): hi at +0, lo at +16
__device__ __forceinline__ size_t frag_off(int row, int col){
  int fragblk = (row >> 5)*2 + ((row >> 4) & 1);
  int kb   = col >> 5;
  int lane = (row & 15) + (((col & 31) >> 3) << 4);
  int e    = col & 7;
  return (size_t)fragblk*32768 + kb*2048 + lane*32 + e*2;
}

__global__ void gru_init(const float* __restrict__ h0, char* __restrict__ ws){
  unsigned* flags = (unsigned*)ws;
  char* hfrag = ws + OFF_HFRAG;
  int tid = blockIdx.x * blockDim.x + threadIdx.x;
  if (blockIdx.x == 0 && threadIdx.x < 1024) flags[threadIdx.x] = 0u;
  for (int idx = tid; idx < B_DIM*H_DIM; idx += gridDim.x * blockDim.x){
    float h = h0[idx];
    unsigned short hi = f2bf(h);
    unsigned short lo = f2bf(h - bf2f(hi));
    size_t off = frag_off(idx >> 9, idx & 511);
    *(unsigned short*)(hfrag + off)      = hi;
    *(unsigned short*)(hfrag + off + 16) = lo;
  }
}

// transcode x (fp32) into fragment layout: [t][rb 0..15][kb 0..7][lane][hi16|lo16]
__global__ void x_transcode(const float* __restrict__ x, char* __restrict__ xfrag){
  int gtid = blockIdx.x * blockDim.x + threadIdx.x;
  int w = gtid >> 6, lane = gtid & 63;
  if (w >= T_DIM*16*8) return;
  int t = w >> 7, rem = w & 127, rb = rem >> 3, kb = rem & 7;
  int row = rb*16 + (lane & 15);
  int kq  = (lane >> 4) * 8;
  const float* src = x + ((size_t)row*T_DIM + t)*I_DIMM + kb*32 + kq;
  f32x4 v0 = *(const f32x4*)src;
  f32x4 v1 = *(const f32x4*)(src + 4);
  short8v hi, lo;
  #pragma unroll
  for (int e = 0; e < 4; ++e){
    unsigned short h0b = f2bf(v0[e]), h1b = f2bf(v1[e]);
    hi[e] = (short)h0b;  hi[e+4] = (short)h1b;
    lo[e]   = (short)f2bf(v0[e] - bf2f(h0b));
    lo[e+4] = (short)f2bf(v1[e] - bf2f(h1b));
  }
  char* dst = xfrag + ((size_t)(t*16 + rb)*8 + kb)*2048 + lane*32;
  *(short8v*)dst = hi;
  *(short8v*)(dst + 16) = lo;
}

template<int XF>
__global__ void __launch_bounds__(256, 1) gru_scan(
    const float* __restrict__ x, const float* __restrict__ w_ih,
    const float* __restrict__ b_ih, const float* __restrict__ w_hh,
    const float* __restrict__ b_hh, const float* __restrict__ h0,
    float* __restrict__ out, char* __restrict__ ws)
{
  extern __shared__ unsigned short lds[];
  unsigned short* WAh = lds;
  unsigned short* WAl = WAh + ACOLS*LDK;
  unsigned short* WBh = WAl + ACOLS*LDK;
  unsigned short* WBl = WBh + BCOLS*LDK;
  float* red = (float*)(WBl + BCOLS*LDK);   // [2][16][16]

  unsigned* flagsA = (unsigned*)(ws + OFF_FLAGA);
  unsigned* flagsB = (unsigned*)(ws + OFF_FLAGB);
  char* hfrag  = ws + OFF_HFRAG;
  char* rhfrag = ws + OFF_RHFRAG;
  float* zbuf  = (float*)(ws + OFF_ZBUF);
  const char* xfrag = ws + OFF_XFRAG;

  const int bid = blockIdx.x;
  const int it  = bid & 7;     // batch tile (XCD-swizzle heuristic)
  const int j   = bid >> 3;    // 0..31 hidden slice
  const int tid = threadIdx.x;
  const int lane = tid & 63;
  const int wv   = tid >> 6;
  unsigned* flagA = flagsA + it*32;
  unsigned* flagB = flagsB + it*32;

  // ---- preload weight slices into LDS as bf16 hi/lo ----
  for (int c = 0; c < ACOLS; ++c){
    int g = ACOLS*j + c;
    for (int k = tid; k < KU; k += 256){
      float w = (k < KH) ? w_hh[(size_t)g*KH + k] : w_ih[(size_t)g*KX + (k - KH)];
      unsigned short hi = f2bf(w);
      WAh[c*LDK + k] = hi;
      WAl[c*LDK + k] = f2bf(w - bf2f(hi));
    }
  }
  for (int c = 0; c < BCOLS; ++c){
    int g = 1024 + BCOLS*j + c;
    for (int k = tid; k < KU; k += 256){
      float w = (k < KH) ? w_hh[(size_t)g*KH + k] : w_ih[(size_t)g*KX + (k - KH)];
      unsigned short hi = f2bf(w);
      WBh[c*LDK + k] = hi;
      WBl[c*LDK + k] = f2bf(w - bf2f(hi));
    }
  }
  __syncthreads();

  const int l16 = lane & 15;
  const int lq  = lane >> 4;
  const int kq  = lq * 8;
  const int rowblk  = wv & 1;
  const int colblkA = wv >> 1;
  const int khalf   = wv >> 1;

  const int fragblk = it*2 + rowblk;
  const char* hA_base  = hfrag  + (size_t)fragblk*32768 + lane*32;
  const char* rhB_base = rhfrag + (size_t)fragblk*32768 + lane*32;
  const int arow = it*MT + rowblk*16 + l16;
  const size_t xrow_off = (size_t)arow * (T_DIM*I_DIMM);
  const int ldsA = (colblkA*16 + l16) * LDK;
  const int ldsB = l16 * LDK;

  const int zr = ACOLS*j + colblkA*16 + l16;
  const float biasA = b_ih[zr] + b_hh[zr];
  const int nc = BCOLS*j + l16;
  const float biasB = b_ih[1024 + nc] + b_hh[1024 + nc];
  const int mrow0 = it*MT + rowblk*16 + lq*4;

  const int hcs = zr & 511;                      // r-producer h col (valid for all j)
  size_t off_hv[4];
  #pragma unroll
  for (int r = 0; r < 4; ++r) off_hv[r] = frag_off(mrow0 + r, hcs);
  size_t off_hw[4];                              // h-writer offsets (khalf0)
  #pragma unroll
  for (int r = 0; r < 4; ++r) off_hw[r] = frag_off(mrow0 + r, nc);

  char* rhkb = rhfrag + (size_t)fragblk*32768 + (size_t)((j - 16) & 15)*2048;

  u64 hb0[4][4], hb1[4][4];

  auto LDH = [&](u64 (&buf)[4][4], int c0){
    #pragma unroll
    for (int u = 0; u < 4; ++u){
      const char* p = hA_base + (size_t)(c0*4 + u)*2048;
      buf[u][0] = ld64_cg(p);      buf[u][1] = ld64_cg(p + 8);
      buf[u][2] = ld64_cg(p + 16); buf[u][3] = ld64_cg(p + 24);
    }
  };
  auto PRA = [&](u64 (&buf)[4][4], int c0, f32x4& D){
    #pragma unroll
    for (int u = 0; u < 4; ++u){
      int k0 = (c0*4 + u)*32 + kq;
      u64x2 thi = {buf[u][0], buf[u][1]};
      u64x2 tlo = {buf[u][2], buf[u][3]};
      short8v ah = __builtin_bit_cast(short8v, thi);
      short8v al = __builtin_bit_cast(short8v, tlo);
      short8v bh = *(const short8v*)(WAh + ldsA + k0);
      short8v bl = *(const short8v*)(WAl + ldsA + k0);
      D = mfma16(ah, bh, D); D = mfma16(ah, bl, D); D = mfma16(al, bh, D);
    }
  };
  auto LDR = [&](u64 (&buf)[4][4], int c0){
    #pragma unroll
    for (int u = 0; u < 4; ++u){
      const char* p = rhB_base + (size_t)((khalf*8) + c0*4 + u)*2048;
      buf[u][0] = ld64_cg(p);      buf[u][1] = ld64_cg(p + 8);
      buf[u][2] = ld64_cg(p + 16); buf[u][3] = ld64_cg(p + 24);
    }
  };
  auto PRB = [&](u64 (&buf)[4][4], int c0, f32x4& D){
    #pragma unroll
    for (int u = 0; u < 4; ++u){
      int k0 = ((khalf*8) + c0*4 + u)*32 + kq;
      u64x2 thi = {buf[u][0], buf[u][1]};
      u64x2 tlo = {buf[u][2], buf[u][3]};
      short8v ah = __builtin_bit_cast(short8v, thi);
      short8v al = __builtin_bit_cast(short8v, tlo);
      short8v bh = *(const short8v*)(WBh + ldsB + k0);
      short8v bl = *(const short8v*)(WBl + ldsB + k0);
      D = mfma16(ah, bh, D); D = mfma16(ah, bl, D); D = mfma16(al, bh, D);
    }
  };
  auto XCONV = [&](const float* xp, short8v& ah, short8v& al){
    f32x4 v0 = *(const f32x4*)xp;
    f32x4 v1 = *(const f32x4*)(xp + 4);
    #pragma unroll
    for (int e = 0; e < 4; ++e){
      unsigned short h0b = f2bf(v0[e]), h1b = f2bf(v1[e]);
      ah[e] = (short)h0b;  ah[e+4] = (short)h1b;
      al[e]   = (short)f2bf(v0[e] - bf2f(h0b));
      al[e+4] = (short)f2bf(v1[e] - bf2f(h1b));
    }
  };

  float h_reg[4];
  if (khalf == 0){
    #pragma unroll
    for (int r = 0; r < 4; ++r)
      h_reg[r] = h0[(size_t)(mrow0 + r)*H_DIM + nc];
  }

  for (int t = 0; t < T_DIM; ++t){
    const char* xf_base = xfrag + ((size_t)t*16 + fragblk)*8*2048 + lane*32;
    const float* xt = x + (size_t)t * I_DIMM;

    // ================= phase A =================
    // early flag probe (monotonic flags: a stale positive is still valid)
    unsigned pvA = __hip_atomic_load(flagB + (tid & 31), __ATOMIC_RELAXED,
                                     __HIP_MEMORY_SCOPE_AGENT);
    f32x4 D = {0.f, 0.f, 0.f, 0.f};
    #pragma unroll
    for (int kb = 0; kb < 8; ++kb){                  // x part, overlaps flag wait
      short8v ah, al;
      if (XF){
        const char* p = xf_base + kb*2048;
        ah = *(const short8v*)p;
        al = *(const short8v*)(p + 16);
      } else {
        XCONV(xt + xrow_off + kb*32 + kq, ah, al);
      }
      int k0 = KH + kb*32 + kq;
      short8v bh = *(const short8v*)(WAh + ldsA + k0);
      short8v bl = *(const short8v*)(WAl + ldsA + k0);
      D = mfma16(ah, bh, D); D = mfma16(ah, bl, D); D = mfma16(al, bh, D);
    }
    if (!__all((int)(pvA >= (unsigned)t)))
      spin_ge(flagB, (unsigned)t);                   // h(t-1) ready (all 32)
    asm volatile("" ::: "memory");

    unsigned hvh[4], hvl[4];                         // r-producer h(t-1) gather only
    if (j >= 16){
      #pragma unroll
      for (int r = 0; r < 4; ++r){
        hvh[r] = ld16_cg(hfrag + off_hv[r]);
        hvl[r] = ld16_cg(hfrag + off_hv[r] + 16);
      }
    }
    LDH(hb0, 0); LDH(hb1, 1);                        // 2-deep chunk pipeline
    PRA(hb0, 0, D); LDH(hb0, 2);
    PRA(hb1, 1, D); LDH(hb1, 3);
    PRA(hb0, 2, D); PRA(hb1, 3, D);

    if (j < 16){                                     // z producer
      #pragma unroll
      for (int r = 0; r < 4; ++r){
        float a = D[r] + biasA;
        float zv = 1.f / (1.f + __expf(-a));
        stf_cg(zbuf + (size_t)(mrow0 + r)*H_DIM + zr, zv);
      }
    } else {                                         // r producer -> rh fragments
      #pragma unroll
      for (int r = 0; r < 4; ++r){
        float a = D[r] + biasA;
        float rv = 1.f / (1.f + __expf(-a));
        float rh = rv * (bf2f((unsigned short)hvh[r]) + bf2f((unsigned short)hvl[r]));
        unsigned short hi = f2bf(rh);
        unsigned short lo = f2bf(rh - bf2f(hi));
        size_t fo = off_hv[r] - ((size_t)fragblk*32768 + (size_t)((j-16)&15)*2048);
        st16_cg(rhkb + fo,      (unsigned)hi);
        st16_cg(rhkb + fo + 16, (unsigned)lo);
      }
    }
    VMCNT0();
    __syncthreads();
    if (tid == 0)
      __hip_atomic_store(flagA + j, (unsigned)(t+1), __ATOMIC_RELAXED,
                         __HIP_MEMORY_SCOPE_AGENT);

    // ================= phase B =================
    unsigned pvB = __hip_atomic_load(flagA + (tid & 31), __ATOMIC_RELAXED,
                                     __HIP_MEMORY_SCOPE_AGENT);
    f32x4 Dn = {0.f, 0.f, 0.f, 0.f};
    #pragma unroll
    for (int u = 0; u < 4; ++u){                     // x part, overlaps flag wait
      int kb = khalf*4 + u;
      short8v ah, al;
      if (XF){
        const char* p = xf_base + kb*2048;
        ah = *(const short8v*)p;
        al = *(const short8v*)(p + 16);
      } else {
        XCONV(xt + xrow_off + kb*32 + kq, ah, al);
      }
      int k0 = KH + kb*32 + kq;
      short8v bh = *(const short8v*)(WBh + ldsB + k0);
      short8v bl = *(const short8v*)(WBl + ldsB + k0);
      Dn = mfma16(ah, bh, Dn); Dn = mfma16(ah, bl, Dn); Dn = mfma16(al, bh, Dn);
    }
    if (!__all((int)(pvB >= (unsigned)(t+1))))
      spin_ge(flagA, (unsigned)(t+1));               // zr/rh ready AND h-reads done
    asm volatile("" ::: "memory");

    float zv[4];
    if (khalf == 0){                                 // z prefetch (consumer only)
      #pragma unroll
      for (int r = 0; r < 4; ++r)
        zv[r] = ldf_cg(zbuf + (size_t)(mrow0 + r)*H_DIM + nc);
    }
    LDR(hb0, 0); LDR(hb1, 1);
    PRB(hb0, 0, Dn);
    PRB(hb1, 1, Dn);

    if (khalf == 1){                                 // partial-K reduce via LDS
      #pragma unroll
      for (int r = 0; r < 4; ++r)
        red[rowblk*256 + (lq*4 + r)*16 + l16] = Dn[r];
    }
    __syncthreads();
    float hn[4];
    if (khalf == 0){
      #pragma unroll
      for (int r = 0; r < 4; ++r){
        float a = Dn[r] + red[rowblk*256 + (lq*4 + r)*16 + l16] + biasB;
        float ea = __expf(2.f * fabsf(a));           // overflow-safe tanh
        float nv = 1.f - 2.f / (ea + 1.f);
        nv = (a < 0.f) ? -nv : nv;
        float hnv = zv[r]*h_reg[r] + (1.f - zv[r])*nv;
        hnv = fminf(5.f, fmaxf(-5.f, hnv));
        unsigned short hi = f2bf(hnv);
        unsigned short lo = f2bf(hnv - bf2f(hi));
        st16_cg(hfrag + off_hw[r],      (unsigned)hi);
        st16_cg(hfrag + off_hw[r] + 16, (unsigned)lo);
        h_reg[r] = hnv;
        hn[r] = hnv;
      }
    }
    VMCNT0();
    __syncthreads();
    if (tid == 0)
      __hip_atomic_store(flagB + j, (unsigned)(t+1), __ATOMIC_RELAXED,
                         __HIP_MEMORY_SCOPE_AGENT);
    if (khalf == 0){                                 // out stores AFTER flag release:
      #pragma unroll                                 // HBM acks leave the critical path
      for (int r = 0; r < 4; ++r){
        int row = mrow0 + r;
        out[(size_t)row*(T_DIM*H_DIM) + (size_t)t*H_DIM + nc] = hn[r];
        if (t == T_DIM - 1)
          out[(size_t)B_DIM*T_DIM*H_DIM + (size_t)row*H_DIM + nc] = hn[r];
      }
    }
  }
}

extern "C" void kernel_launch(void* const* d_in, const int* in_sizes, int n_in,
                              void* d_out, int out_size, void* d_ws, size_t ws_size,
                              hipStream_t stream){
  const float* x    = (const float*)d_in[0];
  const float* h0   = (const float*)d_in[1];
  const float* w_ih = (const float*)d_in[2];
  const float* b_ih = (const float*)d_in[3];
  const float* w_hh = (const float*)d_in[4];
  const float* b_hh = (const float*)d_in[5];
  float* out = (float*)d_out;
  char* ws = (char*)d_ws;

  gru_init<<<128, 256, 0, stream>>>(h0, ws);

  if (ws_size >= WS_NEED){
    x_transcode<<<(T_DIM*16*8*64 + 255)/256, 256, 0, stream>>>(x, ws + OFF_XFRAG);
    hipFuncSetAttribute((const void*)gru_scan<1>,
                        hipFuncAttributeMaxDynamicSharedMemorySize, LDS_BYTES);
    gru_scan<1><<<256, 256, LDS_BYTES, stream>>>(x, w_ih, b_ih, w_hh, b_hh, h0, out, ws);
  } else {
    hipFuncSetAttribute((const void*)gru_scan<0>,
                        hipFuncAttributeMaxDynamicSharedMemorySize, LDS_BYTES);
    gru_scan<0><<<256, 256, LDS_BYTES, stream>>>(x, w_ih, b_ih, w_hh, b_hh, h0, out, ws);
  }
}

// Round 12
// 4612.449 us; speedup vs baseline: 1.3258x; 1.3258x over previous
//
#include <hip/hip_runtime.h>
#include <stdint.h>

#define B_DIM 256
#define T_DIM 400
#define I_DIMM 256
#define H_DIM 512
#define KH 512      // hidden K
#define KX 256      // input K
#define KU 768      // unified K
#define MT 32       // batch rows per workgroup
#define ACOLS 32    // phase-A (zr) output cols per wg
#define BCOLS 16    // phase-B (n) output cols per wg
#define LDK 776     // padded LDS row pitch (bf16 elems)

#define LDS_USHORTS (2*ACOLS*LDK + 2*BCOLS*LDK)
#define LDS_BYTES   (LDS_USHORTS*2 + 512*4)

// ws layout (bytes)
#define OFF_FLAGA 0
#define OFF_FLAGB 2048
#define OFF_HFRAG 4096
#define FRAG_BYTES (16*16*64*32)          // 16 fragblk x 16 kb x 64 lane x 32B = 512KB
#define OFF_RHFRAG (OFF_HFRAG + FRAG_BYTES)
#define OFF_ZBUF   (OFF_RHFRAG + FRAG_BYTES)
#define OFF_XFRAG  (OFF_ZBUF + B_DIM*H_DIM*4)
#define XFRAG_BYTES ((size_t)T_DIM*16*8*2048)          // 100 MB
#define WS_NEED    ((size_t)OFF_XFRAG + XFRAG_BYTES)

typedef __attribute__((ext_vector_type(8))) short short8v;
typedef __attribute__((ext_vector_type(4))) float f32x4;
typedef __attribute__((ext_vector_type(2))) unsigned long long u64x2;

__device__ __forceinline__ unsigned short f2bf(float f){
  unsigned u = __builtin_bit_cast(unsigned, f);
  unsigned r = (u + 0x7fffu + ((u >> 16) & 1u)) >> 16;   // RNE
  return (unsigned short)r;
}
__device__ __forceinline__ float bf2f(unsigned short u){
  return __builtin_bit_cast(float, ((unsigned)u) << 16);
}
__device__ __forceinline__ f32x4 mfma16(short8v a, short8v b, f32x4 c){
  return __builtin_amdgcn_mfma_f32_16x16x32_bf16(a, b, c, 0, 0, 0);
}

// ---- device-coherent (LLC, fence-free) access helpers ----
__device__ __forceinline__ unsigned long long ld64_cg(const void* p){
  return __hip_atomic_load((const unsigned long long*)p, __ATOMIC_RELAXED,
                           __HIP_MEMORY_SCOPE_AGENT);
}
__device__ __forceinline__ unsigned short ld16_cg(const void* p){
  return __hip_atomic_load((const unsigned short*)p, __ATOMIC_RELAXED,
                           __HIP_MEMORY_SCOPE_AGENT);
}
__device__ __forceinline__ float ldf_cg(const float* p){
  return __hip_atomic_load(p, __ATOMIC_RELAXED, __HIP_MEMORY_SCOPE_AGENT);
}
__device__ __forceinline__ void st16_cg(void* p, unsigned v){
  asm volatile("global_store_short %0, %1, off sc0 sc1" :: "v"(p), "v"(v) : "memory");
}
__device__ __forceinline__ void stf_cg(float* p, float v){
  asm volatile("global_store_dword %0, %1, off sc0 sc1" :: "v"(p), "v"(v) : "memory");
}
#define VMCNT0() asm volatile("s_waitcnt vmcnt(0)" ::: "memory")

// wait until all 32 flags >= target (bypassing relaxed polls)
__device__ __forceinline__ void spin_ge(const unsigned* f, unsigned target){
  const unsigned* p = f + (threadIdx.x & 31);
  for (;;){
    unsigned v = __hip_atomic_load(p, __ATOMIC_RELAXED, __HIP_MEMORY_SCOPE_AGENT);
    if (__all((int)(v >= target))) break;
    __builtin_amdgcn_s_sleep(1);
  }
  asm volatile("" ::: "memory");
}

// fragment address of element (row, col) in a frag buffer (hi at +0, lo at +16)
__device__ __forceinline__ size_t frag_off(int row, int col){
  int fragblk = (row >> 5)*2 + ((row >> 4) & 1);
  int kb   = col >> 5;
  int lane = (row & 15) + (((col & 31) >> 3) << 4);
  int e    = col & 7;
  return (size_t)fragblk*32768 + kb*2048 + lane*32 + e*2;
}

__global__ void gru_init(const float* __restrict__ h0, char* __restrict__ ws){
  unsigned* flags = (unsigned*)ws;
  char* hfrag = ws + OFF_HFRAG;
  int tid = blockIdx.x * blockDim.x + threadIdx.x;
  if (blockIdx.x == 0 && threadIdx.x < 1024) flags[threadIdx.x] = 0u;
  for (int idx = tid; idx < B_DIM*H_DIM; idx += gridDim.x * blockDim.x){
    float h = h0[idx];
    unsigned short hi = f2bf(h);
    unsigned short lo = f2bf(h - bf2f(hi));
    size_t off = frag_off(idx >> 9, idx & 511);
    *(unsigned short*)(hfrag + off)      = hi;
    *(unsigned short*)(hfrag + off + 16) = lo;
  }
}

// transcode x (fp32) into fragment layout: [t][rb 0..15][kb 0..7][lane][hi16|lo16]
__global__ void x_transcode(const float* __restrict__ x, char* __restrict__ xfrag){
  int gtid = blockIdx.x * blockDim.x + threadIdx.x;
  int w = gtid >> 6, lane = gtid & 63;
  if (w >= T_DIM*16*8) return;
  int t = w >> 7, rem = w & 127, rb = rem >> 3, kb = rem & 7;
  int row = rb*16 + (lane & 15);
  int kq  = (lane >> 4) * 8;
  const float* src = x + ((size_t)row*T_DIM + t)*I_DIMM + kb*32 + kq;
  f32x4 v0 = *(const f32x4*)src;
  f32x4 v1 = *(const f32x4*)(src + 4);
  short8v hi, lo;
  #pragma unroll
  for (int e = 0; e < 4; ++e){
    unsigned short h0b = f2bf(v0[e]), h1b = f2bf(v1[e]);
    hi[e] = (short)h0b;  hi[e+4] = (short)h1b;
    lo[e]   = (short)f2bf(v0[e] - bf2f(h0b));
    lo[e+4] = (short)f2bf(v1[e] - bf2f(h1b));
  }
  char* dst = xfrag + ((size_t)(t*16 + rb)*8 + kb)*2048 + lane*32;
  *(short8v*)dst = hi;
  *(short8v*)(dst + 16) = lo;
}

template<int XF>
__global__ void __launch_bounds__(256, 1) gru_scan(
    const float* __restrict__ x, const float* __restrict__ w_ih,
    const float* __restrict__ b_ih, const float* __restrict__ w_hh,
    const float* __restrict__ b_hh, const float* __restrict__ h0,
    float* __restrict__ out, char* __restrict__ ws)
{
  extern __shared__ unsigned short lds[];
  unsigned short* WAh = lds;
  unsigned short* WAl = WAh + ACOLS*LDK;
  unsigned short* WBh = WAl + ACOLS*LDK;
  unsigned short* WBl = WBh + BCOLS*LDK;
  float* red = (float*)(WBl + BCOLS*LDK);   // [2][16][16]

  unsigned* flagsA = (unsigned*)(ws + OFF_FLAGA);
  unsigned* flagsB = (unsigned*)(ws + OFF_FLAGB);
  char* hfrag  = ws + OFF_HFRAG;
  char* rhfrag = ws + OFF_RHFRAG;
  float* zbuf  = (float*)(ws + OFF_ZBUF);
  const char* xfrag = ws + OFF_XFRAG;

  const int bid = blockIdx.x;
  const int it  = bid & 7;     // batch tile (XCD-swizzle heuristic)
  const int j   = bid >> 3;    // 0..31 hidden slice
  const int tid = threadIdx.x;
  const int lane = tid & 63;
  const int wv   = tid >> 6;
  unsigned* flagA = flagsA + it*32;
  unsigned* flagB = flagsB + it*32;

  // ---- preload weight slices into LDS as bf16 hi/lo ----
  for (int c = 0; c < ACOLS; ++c){
    int g = ACOLS*j + c;
    for (int k = tid; k < KU; k += 256){
      float w = (k < KH) ? w_hh[(size_t)g*KH + k] : w_ih[(size_t)g*KX + (k - KH)];
      unsigned short hi = f2bf(w);
      WAh[c*LDK + k] = hi;
      WAl[c*LDK + k] = f2bf(w - bf2f(hi));
    }
  }
  for (int c = 0; c < BCOLS; ++c){
    int g = 1024 + BCOLS*j + c;
    for (int k = tid; k < KU; k += 256){
      float w = (k < KH) ? w_hh[(size_t)g*KH + k] : w_ih[(size_t)g*KX + (k - KH)];
      unsigned short hi = f2bf(w);
      WBh[c*LDK + k] = hi;
      WBl[c*LDK + k] = f2bf(w - bf2f(hi));
    }
  }
  __syncthreads();

  const int l16 = lane & 15;
  const int lq  = lane >> 4;
  const int kq  = lq * 8;
  const int rowblk  = wv & 1;
  const int colblkA = wv >> 1;
  const int khalf   = wv >> 1;

  const int fragblk = it*2 + rowblk;
  const char* hA_base  = hfrag  + (size_t)fragblk*32768 + lane*32;  // phase-A A-frags
  const char* rhB_base = rhfrag + (size_t)fragblk*32768 + lane*32;  // phase-B A-frags
  const int arow = it*MT + rowblk*16 + l16;
  const size_t xrow_off = (size_t)arow * (T_DIM*I_DIMM);
  const int ldsA = (colblkA*16 + l16) * LDK;
  const int ldsB = l16 * LDK;

  const int zr = ACOLS*j + colblkA*16 + l16;             // phase-A out col
  const float biasA = b_ih[zr] + b_hh[zr];
  const int nc = BCOLS*j + l16;                          // phase-B out col
  const float biasB = b_ih[1024 + nc] + b_hh[1024 + nc];
  const int mrow0 = it*MT + rowblk*16 + lq*4;

  // precomputed exchange offsets
  const int hcs = zr & 511;                              // r-producer h column
  size_t off_hv[4];                                      // element offsets
  #pragma unroll
  for (int r = 0; r < 4; ++r) off_hv[r] = frag_off(mrow0 + r, hcs);
  size_t off_hw[4];                                      // h-writer offsets (khalf0)
  #pragma unroll
  for (int r = 0; r < 4; ++r) off_hw[r] = frag_off(mrow0 + r, nc);

  // phase-B epilogue h(t-1) in registers
  float h_reg[4];
  if (khalf == 0){
    #pragma unroll
    for (int r = 0; r < 4; ++r)
      h_reg[r] = h0[(size_t)(mrow0 + r)*H_DIM + nc];
  }

  unsigned long long hb0[4][4], hb1[4][4];

  auto LDH = [&](unsigned long long (&buf)[4][4], int c0){
    #pragma unroll
    for (int u = 0; u < 4; ++u){
      const char* p = hA_base + (size_t)(c0*4 + u)*2048;
      buf[u][0] = ld64_cg(p);      buf[u][1] = ld64_cg(p + 8);
      buf[u][2] = ld64_cg(p + 16); buf[u][3] = ld64_cg(p + 24);
    }
  };
  auto PRA = [&](unsigned long long (&buf)[4][4], int c0, f32x4& D){
    #pragma unroll
    for (int u = 0; u < 4; ++u){
      int k0 = (c0*4 + u)*32 + kq;
      u64x2 thi = {buf[u][0], buf[u][1]};
      u64x2 tlo = {buf[u][2], buf[u][3]};
      short8v ah = __builtin_bit_cast(short8v, thi);
      short8v al = __builtin_bit_cast(short8v, tlo);
      short8v bh = *(const short8v*)(WAh + ldsA + k0);
      short8v bl = *(const short8v*)(WAl + ldsA + k0);
      D = mfma16(ah, bh, D);
      D = mfma16(ah, bl, D);
      D = mfma16(al, bh, D);
    }
  };
  auto LDR = [&](unsigned long long (&buf)[4][4], int c0){
    #pragma unroll
    for (int u = 0; u < 4; ++u){
      const char* p = rhB_base + (size_t)((khalf*8) + c0*4 + u)*2048;
      buf[u][0] = ld64_cg(p);      buf[u][1] = ld64_cg(p + 8);
      buf[u][2] = ld64_cg(p + 16); buf[u][3] = ld64_cg(p + 24);
    }
  };
  auto PRB = [&](unsigned long long (&buf)[4][4], int c0, f32x4& D){
    #pragma unroll
    for (int u = 0; u < 4; ++u){
      int k0 = ((khalf*8) + c0*4 + u)*32 + kq;
      u64x2 thi = {buf[u][0], buf[u][1]};
      u64x2 tlo = {buf[u][2], buf[u][3]};
      short8v ah = __builtin_bit_cast(short8v, thi);
      short8v al = __builtin_bit_cast(short8v, tlo);
      short8v bh = *(const short8v*)(WBh + ldsB + k0);
      short8v bl = *(const short8v*)(WBl + ldsB + k0);
      D = mfma16(ah, bh, D);
      D = mfma16(ah, bl, D);
      D = mfma16(al, bh, D);
    }
  };
  // fallback on-the-fly x conversion
  auto XCONV = [&](const float* xp, short8v& ah, short8v& al){
    f32x4 v0 = *(const f32x4*)xp;
    f32x4 v1 = *(const f32x4*)(xp + 4);
    #pragma unroll
    for (int e = 0; e < 4; ++e){
      unsigned short h0b = f2bf(v0[e]), h1b = f2bf(v1[e]);
      ah[e] = (short)h0b;  ah[e+4] = (short)h1b;
      al[e]   = (short)f2bf(v0[e] - bf2f(h0b));
      al[e+4] = (short)f2bf(v1[e] - bf2f(h1b));
    }
  };

  for (int t = 0; t < T_DIM; ++t){
    const char* xf_base = xfrag + ((size_t)t*16 + fragblk)*8*2048 + lane*32;
    const float* xt = x + (size_t)t * I_DIMM;

    // ================= phase A =================
    f32x4 D = {0.f, 0.f, 0.f, 0.f};
    #pragma unroll
    for (int kb = 0; kb < 8; ++kb){                      // x part (pre-spin)
      short8v ah, al;
      if (XF){
        const char* p = xf_base + kb*2048;
        ah = *(const short8v*)p;
        al = *(const short8v*)(p + 16);
      } else {
        XCONV(xt + xrow_off + kb*32 + kq, ah, al);
      }
      int k0 = KH + kb*32 + kq;
      short8v bh = *(const short8v*)(WAh + ldsA + k0);
      short8v bl = *(const short8v*)(WAl + ldsA + k0);
      D = mfma16(ah, bh, D);
      D = mfma16(ah, bl, D);
      D = mfma16(al, bh, D);
    }

    spin_ge(flagB, (unsigned)t);                         // h(t-1) ready

    // r-producer h(t-1) elements (uniform; j<16 loads unused valid data)
    unsigned short hvh[4], hvl[4];
    #pragma unroll
    for (int r = 0; r < 4; ++r){
      hvh[r] = ld16_cg(hfrag + off_hv[r]);
      hvl[r] = ld16_cg(hfrag + off_hv[r] + 16);
    }

    // h part: 16 kb in 4 chunks, 2-deep pipeline
    LDH(hb0, 0); LDH(hb1, 1);
    PRA(hb0, 0, D); LDH(hb0, 2);
    PRA(hb1, 1, D); LDH(hb1, 3);
    PRA(hb0, 2, D); PRA(hb1, 3, D);

    if (j < 16){                                         // z producer
      #pragma unroll
      for (int r = 0; r < 4; ++r){
        float a = D[r] + biasA;
        float zv = 1.f / (1.f + __expf(-a));
        stf_cg(zbuf + (size_t)(mrow0 + r)*H_DIM + zr, zv);
      }
    } else {                                             // r producer -> rh frags
      #pragma unroll
      for (int r = 0; r < 4; ++r){
        float a = D[r] + biasA;
        float rv = 1.f / (1.f + __expf(-a));
        float rh = rv * (bf2f(hvh[r]) + bf2f(hvl[r]));
        unsigned short hi = f2bf(rh);
        unsigned short lo = f2bf(rh - bf2f(hi));
        st16_cg(rhfrag + off_hv[r],      (unsigned)hi);
        st16_cg(rhfrag + off_hv[r] + 16, (unsigned)lo);
      }
    }
    VMCNT0();
    __syncthreads();
    if (tid == 0)
      __hip_atomic_store(flagA + j, (unsigned)(t+1), __ATOMIC_RELAXED,
                         __HIP_MEMORY_SCOPE_AGENT);

    // ================= phase B =================
    f32x4 Dn = {0.f, 0.f, 0.f, 0.f};
    #pragma unroll
    for (int u = 0; u < 4; ++u){                         // x part (pre-spin), K split
      int kb = khalf*4 + u;
      short8v ah, al;
      if (XF){
        const char* p = xf_base + kb*2048;
        ah = *(const short8v*)p;
        al = *(const short8v*)(p + 16);
      } else {
        XCONV(xt + xrow_off + kb*32 + kq, ah, al);
      }
      int k0 = KH + kb*32 + kq;
      short8v bh = *(const short8v*)(WBh + ldsB + k0);
      short8v bl = *(const short8v*)(WBl + ldsB + k0);
      Dn = mfma16(ah, bh, Dn);
      Dn = mfma16(ah, bl, Dn);
      Dn = mfma16(al, bh, Dn);
    }

    spin_ge(flagA, (unsigned)(t+1));                     // zr/rh ready

    float zv[4];
    #pragma unroll
    for (int r = 0; r < 4; ++r)                          // uniform prefetch
      zv[r] = ldf_cg(zbuf + (size_t)(mrow0 + r)*H_DIM + nc);

    // rh part: 8 kb in 2 chunks
    LDR(hb0, 0); LDR(hb1, 1);
    PRB(hb0, 0, Dn); PRB(hb1, 1, Dn);

    if (khalf == 1){
      #pragma unroll
      for (int r = 0; r < 4; ++r)
        red[rowblk*256 + (lq*4 + r)*16 + l16] = Dn[r];
    }
    __syncthreads();
    if (khalf == 0){
      #pragma unroll
      for (int r = 0; r < 4; ++r){
        float a = Dn[r] + red[rowblk*256 + (lq*4 + r)*16 + l16] + biasB;
        float ea = __expf(2.f * fabsf(a));
        float nv = 1.f - 2.f / (ea + 1.f);
        nv = (a < 0.f) ? -nv : nv;
        int row = mrow0 + r;
        float hn = zv[r]*h_reg[r] + (1.f - zv[r])*nv;
        hn = fminf(5.f, fmaxf(-5.f, hn));
        unsigned short hi = f2bf(hn);
        unsigned short lo = f2bf(hn - bf2f(hi));
        st16_cg(hfrag + off_hw[r],      (unsigned)hi);
        st16_cg(hfrag + off_hw[r] + 16, (unsigned)lo);
        out[(size_t)row*(T_DIM*H_DIM) + (size_t)t*H_DIM + nc] = hn;
        h_reg[r] = hn;
        if (t == T_DIM - 1)
          out[(size_t)B_DIM*T_DIM*H_DIM + (size_t)row*H_DIM + nc] = hn;  // h_last
      }
    }
    VMCNT0();
    __syncthreads();
    if (tid == 0)
      __hip_atomic_store(flagB + j, (unsigned)(t+1), __ATOMIC_RELAXED,
                         __HIP_MEMORY_SCOPE_AGENT);
  }
}

extern "C" void kernel_launch(void* const* d_in, const int* in_sizes, int n_in,
                              void* d_out, int out_size, void* d_ws, size_t ws_size,
                              hipStream_t stream){
  const float* x    = (const float*)d_in[0];
  const float* h0   = (const float*)d_in[1];
  const float* w_ih = (const float*)d_in[2];
  const float* b_ih = (const float*)d_in[3];
  const float* w_hh = (const float*)d_in[4];
  const float* b_hh = (const float*)d_in[5];
  float* out = (float*)d_out;
  char* ws = (char*)d_ws;

  gru_init<<<128, 256, 0, stream>>>(h0, ws);

  if (ws_size >= WS_NEED){
    x_transcode<<<(T_DIM*16*8*64 + 255)/256, 256, 0, stream>>>(x, ws + OFF_XFRAG);
    hipFuncSetAttribute((const void*)gru_scan<1>,
                        hipFuncAttributeMaxDynamicSharedMemorySize, LDS_BYTES);
    gru_scan<1><<<256, 256, LDS_BYTES, stream>>>(x, w_ih, b_ih, w_hh, b_hh, h0,
                                                 out, ws);
  } else {
    hipFuncSetAttribute((const void*)gru_scan<0>,
                        hipFuncAttributeMaxDynamicSharedMemorySize, LDS_BYTES);
    gru_scan<0><<<256, 256, LDS_BYTES, stream>>>(x, w_ih, b_ih, w_hh, b_hh, h0,
                                                 out, ws);
  }
}